// Round 6
// baseline (567.484 us; speedup 1.0000x reference)
//
#include <hip/hip_runtime.h>

#define DEV __device__ __forceinline__
typedef unsigned short u16;
typedef unsigned int u32;
typedef __bf16 bf16x8 __attribute__((ext_vector_type(8)));
typedef float f32x4 __attribute__((ext_vector_type(4)));

static constexpr int B = 8192, T = 90, F = 7, H = 128, NOUT = 30;

DEV float fexp2(float x) { return __builtin_amdgcn_exp2f(x); }
DEV float frcp(float x) { return __builtin_amdgcn_rcpf(x); }
DEV float frsq(float x) { return __builtin_amdgcn_rsqf(x); }
DEV float sigm(float x) { return frcp(1.f + fexp2(-1.44269504088896341f * x)); }
DEV u16 f2bfbits(float f) { __bf16 b = (__bf16)f; return __builtin_bit_cast(u16, b); }
DEV float bfbits2f(u32 u) { return __builtin_bit_cast(float, u << 16); }
DEV u32 pk2(float a, float b) { return (u32)f2bfbits(a) | ((u32)f2bfbits(b) << 16); }

DEV float wave_sum(float v) {
#pragma unroll
    for (int m = 32; m; m >>= 1) v += __shfl_xor(v, m, 64);
    return v;
}

// ---------------------------------------------------------------------------
// prep_aux (1 block): LN-folded layer-1 input operator.
//   aux[0..6]=m, aux[7]=mean(b_in), aux[8+7c+d]=Q, aux[64..70]=p, aux[72]=r.
//   Uhat[512][32] bf16: with z=[rstd*x(7), rstd, -rstd*mu, 1, 0...],
//   Uhat·z == Wih0·LN(W_in x + b_in).
// ---------------------------------------------------------------------------
__global__ __launch_bounds__(512) void prep_aux(
    const float* __restrict__ W_in, const float* __restrict__ b_in,
    const float* __restrict__ g_in, const float* __restrict__ be_in,
    const float* __restrict__ Wih0, float* __restrict__ aux, u16* __restrict__ Uhat) {
    const int tid = threadIdx.x;
    if (tid < 7) {
        float sm = 0.f, sp = 0.f;
        for (int h = 0; h < 128; ++h) { const float w = W_in[h * 7 + tid]; sm += w; sp += w * b_in[h]; }
        aux[tid] = sm * (1.f / 128.f); aux[64 + tid] = sp * (1.f / 128.f);
    } else if (tid < 56) {
        const int cd = tid - 7, cc = cd / 7, dd = cd % 7;
        float s = 0.f;
        for (int h = 0; h < 128; ++h) s += W_in[h * 7 + cc] * W_in[h * 7 + dd];
        aux[8 + cd] = s * (1.f / 128.f);
    } else if (tid == 56) {
        float s = 0.f; for (int h = 0; h < 128; ++h) s += b_in[h];
        aux[7] = s * (1.f / 128.f);
    } else if (tid == 57) {
        float s = 0.f; for (int h = 0; h < 128; ++h) s += b_in[h] * b_in[h];
        aux[72] = s * (1.f / 128.f);
    }
    float acc[10];
#pragma unroll
    for (int i = 0; i < 10; ++i) acc[i] = 0.f;
    const float* wr = Wih0 + (long)tid * 128;
    for (int h = 0; h < 128; ++h) {
        const float wv = wr[h], wg = wv * g_in[h];
#pragma unroll
        for (int cc = 0; cc < 7; ++cc) acc[cc] += wg * W_in[h * 7 + cc];
        acc[7] += wg * b_in[h]; acc[8] += wg; acc[9] += wv * be_in[h];
    }
    u16* dst = Uhat + tid * 32;
#pragma unroll
    for (int cc = 0; cc < 10; ++cc) dst[cc] = f2bfbits(acc[cc]);
#pragma unroll
    for (int cc = 10; cc < 32; ++cc) dst[cc] = 0;
}

// ---------------------------------------------------------------------------
// cvt3: bf16 row-major copies of Whh0, Wih1, Whh1 (each 512x128).
// ---------------------------------------------------------------------------
__global__ __launch_bounds__(256) void cvt3(
    const float* __restrict__ a, const float* __restrict__ b,
    const float* __restrict__ c, u16* __restrict__ dst) {
    const long i = (long)blockIdx.x * 256 + threadIdx.x;
    const int which = (int)(i >> 14);
    const long off = (i & 16383) * 4;
    const float* src = which == 0 ? a : (which == 1 ? b : c);
    const float4 v = *(const float4*)(src + off);
    u32 p0 = pk2(v.x, v.y), p1 = pk2(v.z, v.w);
    *(uint2*)(dst + (long)which * 65536 + off) = (uint2){p0, p1};
}

// ---------------------------------------------------------------------------
// prep_stats: per (b,t) closed-form rstd, -rstd*mu of the layer-1 LN input.
// ---------------------------------------------------------------------------
__global__ __launch_bounds__(256) void prep_stats(
    const float* __restrict__ x, const float* __restrict__ aux,
    float2* __restrict__ stats) {
    __shared__ float sa[80];
    const int tid = threadIdx.x;
    if (tid < 80) sa[tid] = aux[tid];
    __syncthreads();
    const long idx = (long)blockIdx.x * 256 + tid;
    const float* xr = x + idx * 7;
    float xv[7];
#pragma unroll
    for (int cc = 0; cc < 7; ++cc) xv[cc] = xr[cc];
    float mu = sa[7];
#pragma unroll
    for (int cc = 0; cc < 7; ++cc) mu += sa[cc] * xv[cc];
    float q = sa[72];
#pragma unroll
    for (int cc = 0; cc < 7; ++cc) {
        float tacc = 2.f * sa[64 + cc];
#pragma unroll
        for (int dd = 0; dd < 7; ++dd) tacc += sa[8 + cc * 7 + dd] * xv[dd];
        q += xv[cc] * tacc;
    }
    const float rstd = frsq(q - mu * mu + 1e-5f);
    stats[idx] = make_float2(rstd, -rstd * mu);
}

// ---------------------------------------------------------------------------
// Layer-1 LSTM: 512 thr (8 waves, each owning 16 h-cols -> full 128), 32
// rows split into TWO interleaved 16-row tiles (A/B). Each half-iteration:
// MFMA for tile P step t (issues first), then gate-VALU for tile Q from the
// previous half's accumulators (fills the MFMA shadow), one barrier.
// x-side = K=32 augmented-z MFMA (LN folded); h-side K=128.
// MFMA 16x16x32 bf16; A[m=lane&15][k=quad*8+j]; C/D col=lane&15,row=quad*4+reg.
// ---------------------------------------------------------------------------
__global__ __launch_bounds__(512, 2) void lstm_rec_l1(
    const float* __restrict__ x, const float2* __restrict__ stats,
    const u16* __restrict__ Uhat, const u16* __restrict__ Whhb,
    const float* __restrict__ bih, const float* __restrict__ bhh,
    u16* __restrict__ hs) {
    __shared__ __align__(16) u16 s_z[2][3][4][16][8];  // [tile][buf][kk8][m][8] 12 KB
    __shared__ __align__(16) u16 s_h[2][2][2048];      // [tile][par][16*128]   16 KB

    const int tid = threadIdx.x;
    const int wave = tid >> 6, lane = tid & 63, quad = lane >> 4, n16 = lane & 15;
    const int b0 = blockIdx.x * 32;

    for (int i = tid; i < 2 * 3 * 4 * 16 * 8; i += 512) ((u16*)s_z)[i] = 0;
    for (int i = tid; i < 2048; i += 512) { s_h[0][1][i] = 0; s_h[1][1][i] = 0; }

    bf16x8 bU[4], bWhh[4][4];
    f32x4 bias4[4];
#pragma unroll
    for (int g = 0; g < 4; ++g) {
        const int wrow = g * 128 + 16 * wave + n16;
        const float bb = bih[wrow] + bhh[wrow];
        bias4[g] = (f32x4){bb, bb, bb, bb};
        bU[g] = *(const bf16x8*)&Uhat[wrow * 32 + quad * 8];
#pragma unroll
        for (int kk = 0; kk < 4; ++kk)
            bWhh[g][kk] = *(const bf16x8*)&Whhb[(long)wrow * 128 + kk * 32 + quad * 8];
    }

    // z stagers: 32 threads; flush threads: tid<256
    const bool zst = (tid < 32);
    const int srow = tid & 15, skk8z = tid >> 4;  // for zst
    const bool stg = (tid < 256);
    const int fm = tid & 15, fkk8 = (tid >> 4) & 15;
    const int fldso = (fkk8 * 16 + fm) * 8;

    auto build_z = [&](size_t sidx, u16* dst) {  // dst = &s_z[P][buf][skk8z][srow][0]
        const float2 st = stats[sidx];
        u32 p0, p1, p2, p3;
        if (skk8z == 0) {
            const float* xp = x + sidx * 7;
            const float rs = st.x;
            p0 = pk2(rs * xp[0], rs * xp[1]); p1 = pk2(rs * xp[2], rs * xp[3]);
            p2 = pk2(rs * xp[4], rs * xp[5]); p3 = pk2(rs * xp[6], rs);
        } else { p0 = pk2(st.y, 1.f); p1 = 0; p2 = 0; p3 = 0; }
        *(uint4*)dst = (uint4){p0, p1, p2, p3};
    };

    __syncthreads();  // zero-init visible

    if (zst) {  // z(0), z(1) for both tiles
#pragma unroll
        for (int tl = 0; tl < 2; ++tl)
#pragma unroll
            for (int tt = 0; tt < 2; ++tt)
                build_z((size_t)(b0 + tl * 16 + srow) * T + tt, &s_z[tl][tt][skk8z][srow][0]);
    }
    __syncthreads();

    auto do_mfma = [&](const u16* szb, const u16* shb, f32x4* gcn) {
        const bf16x8 az = *(const bf16x8*)&szb[(quad * 16 + n16) * 8];
        bf16x8 ah[4];
#pragma unroll
        for (int kk = 0; kk < 4; ++kk)
            ah[kk] = *(const bf16x8*)&shb[((kk * 4 + quad) * 16 + n16) * 8];
#pragma unroll
        for (int g = 0; g < 4; ++g) {
            f32x4 a = __builtin_amdgcn_mfma_f32_16x16x32_bf16(az, bU[g], bias4[g], 0, 0, 0);
#pragma unroll
            for (int kk = 0; kk < 4; ++kk)
                a = __builtin_amdgcn_mfma_f32_16x16x32_bf16(ah[kk], bWhh[g][kk], a, 0, 0, 0);
            gcn[g] = a;
        }
    };
    auto do_gates = [&](const f32x4* gco, float* cc, u16* shout) {
#pragma unroll
        for (int r = 0; r < 4; ++r) {
            const float xi = gco[0][r], xf = gco[1][r], xgg = gco[2][r], xo = gco[3][r];
            const float tg = 2.f * frcp(1.f + fexp2(-2.88539008177792681f * xgg)) - 1.f;
            const float cn = sigm(xf) * cc[r] + sigm(xi) * tg;
            cc[r] = cn;
            const float so = sigm(xo);
            const float rr = frcp(1.f + fexp2(-2.88539008177792681f * cn));
            const float hv = __builtin_fmaf(2.f * so, rr, -so);  // so*tanh(cn)
            shout[((2 * wave + (n16 >> 3)) * 16 + (quad * 4 + r)) * 8 + (n16 & 7)] = f2bfbits(hv);
        }
    };

    float cA[4] = {0.f, 0.f, 0.f, 0.f}, cB[4] = {0.f, 0.f, 0.f, 0.f};
    f32x4 gc[4], gn[4];

#pragma unroll 1
    for (int t2 = 0; t2 < T; ++t2) {
        const int tm = t2 % 3;
        const int tw = (tm >= 1) ? tm - 1 : tm + 2;  // (t2+2)%3
        const int ph = t2 & 1, pho = ph ^ 1;
        const bool hasPre = (t2 + 2 < T);

        // ---------- half A: MFMA (A,t2); gates (B,t2-1) ----------
        do_mfma(&s_z[0][tm][0][0][0], s_h[0][pho], gn);
        if (t2 > 0 && stg) {  // flush h_A(t2-1)
            const uint4 hv = *(const uint4*)&s_h[0][pho][fldso];
            *(uint4*)(hs + ((size_t)(b0 + fm) * T + (t2 - 1)) * 128 + fkk8 * 8) = hv;
        }
        if (t2 > 0) do_gates(gc, cB, s_h[1][pho]);
#pragma unroll
        for (int g = 0; g < 4; ++g) gc[g] = gn[g];
        if (hasPre && zst)
            build_z((size_t)(b0 + srow) * T + t2 + 2, &s_z[0][tw][skk8z][srow][0]);
        __syncthreads();

        // ---------- half B: MFMA (B,t2); gates (A,t2) ----------
        do_mfma(&s_z[1][tm][0][0][0], s_h[1][pho], gn);
        if (t2 > 0 && stg) {  // flush h_B(t2-1)
            const uint4 hv = *(const uint4*)&s_h[1][pho][fldso];
            *(uint4*)(hs + ((size_t)(b0 + 16 + fm) * T + (t2 - 1)) * 128 + fkk8 * 8) = hv;
        }
        do_gates(gc, cA, s_h[0][ph]);
#pragma unroll
        for (int g = 0; g < 4; ++g) gc[g] = gn[g];
        if (hasPre && zst)
            build_z((size_t)(b0 + 16 + srow) * T + t2 + 2, &s_z[1][tw][skk8z][srow][0]);
        __syncthreads();
    }
    // drain: gates (B, T-1) -> parity 1
    do_gates(gc, cB, s_h[1][1]);
    __syncthreads();
    if (stg) {  // h(T-1) for both tiles (parity 1)
        const uint4 hvA = *(const uint4*)&s_h[0][1][fldso];
        const uint4 hvB = *(const uint4*)&s_h[1][1][fldso];
        *(uint4*)(hs + ((size_t)(b0 + fm) * T + (T - 1)) * 128 + fkk8 * 8) = hvA;
        *(uint4*)(hs + ((size_t)(b0 + 16 + fm) * T + (T - 1)) * 128 + fkk8 * 8) = hvB;
    }
}

// ---------------------------------------------------------------------------
// Layer-2 LSTM: same two-tile interleave; x-side K=128 from hs0 (bf16).
// Writes only hlast.
// ---------------------------------------------------------------------------
__global__ __launch_bounds__(512, 2) void lstm_rec_l2(
    const u16* __restrict__ Wihb, const u16* __restrict__ Whhb,
    const float* __restrict__ bih, const float* __restrict__ bhh,
    const u16* __restrict__ xin, u16* __restrict__ hlast) {
    __shared__ __align__(16) u16 s_x[2][3][2048];  // [tile][buf][16*128] 24 KB
    __shared__ __align__(16) u16 s_h[2][2][2048];  // [tile][par][16*128] 16 KB

    const int tid = threadIdx.x;
    const int wave = tid >> 6, lane = tid & 63, quad = lane >> 4, n16 = lane & 15;
    const int b0 = blockIdx.x * 32;

    for (int i = tid; i < 2048; i += 512) { s_h[0][1][i] = 0; s_h[1][1][i] = 0; }

    bf16x8 bWih[4][4], bWhh[4][4];
    f32x4 bias4[4];
#pragma unroll
    for (int g = 0; g < 4; ++g) {
        const int wrow = g * 128 + 16 * wave + n16;
        const float bb = bih[wrow] + bhh[wrow];
        bias4[g] = (f32x4){bb, bb, bb, bb};
#pragma unroll
        for (int kk = 0; kk < 4; ++kk) {
            bWih[g][kk] = *(const bf16x8*)&Wihb[(long)wrow * 128 + kk * 32 + quad * 8];
            bWhh[g][kk] = *(const bf16x8*)&Whhb[(long)wrow * 128 + kk * 32 + quad * 8];
        }
    }

    const bool stg = (tid < 256);
    const int fm = tid & 15, fkk8 = (tid >> 4) & 15;
    const int fldso = (fkk8 * 16 + fm) * 8;
    const u16* gsA = xin + (size_t)(b0 + fm) * T * 128 + fkk8 * 8;
    const u16* gsB = xin + (size_t)(b0 + 16 + fm) * T * 128 + fkk8 * 8;

    if (stg) {  // x(0), x(1) for both tiles
#pragma unroll
        for (int tt = 0; tt < 2; ++tt) {
            *(uint4*)&s_x[0][tt][fldso] = *(const uint4*)(gsA + (size_t)tt * 128);
            *(uint4*)&s_x[1][tt][fldso] = *(const uint4*)(gsB + (size_t)tt * 128);
        }
    }
    __syncthreads();

    auto do_mfma = [&](const u16* sxb, const u16* shb, f32x4* gcn) {
        bf16x8 ax[4], ah[4];
#pragma unroll
        for (int kk = 0; kk < 4; ++kk) {
            ax[kk] = *(const bf16x8*)&sxb[((kk * 4 + quad) * 16 + n16) * 8];
            ah[kk] = *(const bf16x8*)&shb[((kk * 4 + quad) * 16 + n16) * 8];
        }
#pragma unroll
        for (int g = 0; g < 4; ++g) {
            f32x4 a = bias4[g];
#pragma unroll
            for (int kk = 0; kk < 4; ++kk) {
                a = __builtin_amdgcn_mfma_f32_16x16x32_bf16(ax[kk], bWih[g][kk], a, 0, 0, 0);
                a = __builtin_amdgcn_mfma_f32_16x16x32_bf16(ah[kk], bWhh[g][kk], a, 0, 0, 0);
            }
            gcn[g] = a;
        }
    };
    auto do_gates = [&](const f32x4* gco, float* cc, u16* shout) {
#pragma unroll
        for (int r = 0; r < 4; ++r) {
            const float xi = gco[0][r], xf = gco[1][r], xgg = gco[2][r], xo = gco[3][r];
            const float tg = 2.f * frcp(1.f + fexp2(-2.88539008177792681f * xgg)) - 1.f;
            const float cn = sigm(xf) * cc[r] + sigm(xi) * tg;
            cc[r] = cn;
            const float so = sigm(xo);
            const float rr = frcp(1.f + fexp2(-2.88539008177792681f * cn));
            const float hv = __builtin_fmaf(2.f * so, rr, -so);
            shout[((2 * wave + (n16 >> 3)) * 16 + (quad * 4 + r)) * 8 + (n16 & 7)] = f2bfbits(hv);
        }
    };

    float cA[4] = {0.f, 0.f, 0.f, 0.f}, cB[4] = {0.f, 0.f, 0.f, 0.f};
    f32x4 gc[4], gn[4];

#pragma unroll 1
    for (int t2 = 0; t2 < T; ++t2) {
        const int tm = t2 % 3;
        const int tw = (tm >= 1) ? tm - 1 : tm + 2;  // (t2+2)%3
        const int ph = t2 & 1, pho = ph ^ 1;
        const bool hasPre = (t2 + 2 < T);

        // ---------- half A ----------
        uint4 preA = {};
        if (hasPre && stg) preA = *(const uint4*)(gsA + (size_t)(t2 + 2) * 128);
        do_mfma(s_x[0][tm], s_h[0][pho], gn);
        if (t2 > 0) do_gates(gc, cB, s_h[1][pho]);
#pragma unroll
        for (int g = 0; g < 4; ++g) gc[g] = gn[g];
        if (hasPre && stg) *(uint4*)&s_x[0][tw][fldso] = preA;
        __syncthreads();

        // ---------- half B ----------
        uint4 preB = {};
        if (hasPre && stg) preB = *(const uint4*)(gsB + (size_t)(t2 + 2) * 128);
        do_mfma(s_x[1][tm], s_h[1][pho], gn);
        do_gates(gc, cA, s_h[0][ph]);
#pragma unroll
        for (int g = 0; g < 4; ++g) gc[g] = gn[g];
        if (hasPre && stg) *(uint4*)&s_x[1][tw][fldso] = preB;
        __syncthreads();
    }
    do_gates(gc, cB, s_h[1][1]);  // drain: (B, T-1)
    __syncthreads();
    if (stg) {
        const uint4 hvA = *(const uint4*)&s_h[0][1][fldso];
        const uint4 hvB = *(const uint4*)&s_h[1][1][fldso];
        *(uint4*)(hlast + (size_t)(b0 + fm) * 128 + fkk8 * 8) = hvA;
        *(uint4*)(hlast + (size_t)(b0 + 16 + fm) * 128 + fkk8 * 8) = hvB;
    }
}

// ---------------------------------------------------------------------------
// Head: 4 rows per wave, 16 rows per block, grid 512.
// ---------------------------------------------------------------------------
__global__ __launch_bounds__(256) void dense_head(
    const u16* __restrict__ hlast, const float* __restrict__ g_ln,
    const float* __restrict__ be_ln, const float* __restrict__ W_d1,
    const float* __restrict__ b_d1, const float* __restrict__ W_d2,
    const float* __restrict__ b_d2, const float* __restrict__ W_d3,
    const float* __restrict__ b_d3, float* __restrict__ out) {
    __shared__ float s_ln[16][128];
    __shared__ float s_d1[16][128];
    __shared__ float s_d2[16][64];
    const int wave = threadIdx.x >> 6, lane = threadIdx.x & 63;
    const long base = (long)blockIdx.x * 16;
    const int R = wave * 4;

#pragma unroll
    for (int rr = 0; rr < 4; ++rr) {
        const long row = base + R + rr;
        const u32 packed = ((const u32*)hlast)[row * 64 + lane];
        float v0 = bfbits2f(packed & 0xffffu), v1 = bfbits2f(packed >> 16);
        const float s = wave_sum(v0 + v1);
        const float q = wave_sum(v0 * v0 + v1 * v1);
        const float mu = s * (1.f / 128.f);
        const float rstd = frsq(q * (1.f / 128.f) - mu * mu + 1e-5f);
        const int h0 = 2 * lane;
        s_ln[R + rr][h0] = (v0 - mu) * rstd * g_ln[h0] + be_ln[h0];
        s_ln[R + rr][h0 + 1] = (v1 - mu) * rstd * g_ln[h0 + 1] + be_ln[h0 + 1];
    }
    __syncthreads();

#pragma unroll
    for (int half = 0; half < 2; ++half) {
        const int o = lane + 64 * half;
        float a[4] = {b_d1[o], b_d1[o], b_d1[o], b_d1[o]};
        const float4* wr = (const float4*)(W_d1 + (long)o * 128);
#pragma unroll 8
        for (int k = 0; k < 32; ++k) {
            const float4 wv = wr[k];
#pragma unroll
            for (int rr = 0; rr < 4; ++rr) {
                const float4 xv = ((const float4*)s_ln[R + rr])[k];
                a[rr] += wv.x * xv.x + wv.y * xv.y + wv.z * xv.z + wv.w * xv.w;
            }
        }
#pragma unroll
        for (int rr = 0; rr < 4; ++rr) s_d1[R + rr][o] = fmaxf(a[rr], 0.f);
    }
    __syncthreads();

    {
        float a[4] = {b_d2[lane], b_d2[lane], b_d2[lane], b_d2[lane]};
        const float4* wr = (const float4*)(W_d2 + (long)lane * 128);
#pragma unroll 8
        for (int k = 0; k < 32; ++k) {
            const float4 wv = wr[k];
#pragma unroll
            for (int rr = 0; rr < 4; ++rr) {
                const float4 xv = ((const float4*)s_d1[R + rr])[k];
                a[rr] += wv.x * xv.x + wv.y * xv.y + wv.z * xv.z + wv.w * xv.w;
            }
        }
#pragma unroll
        for (int rr = 0; rr < 4; ++rr) s_d2[R + rr][lane] = fmaxf(a[rr], 0.f);
    }
    __syncthreads();

    if (lane < NOUT) {
        float a[4] = {b_d3[lane], b_d3[lane], b_d3[lane], b_d3[lane]};
        const float4* wr = (const float4*)(W_d3 + (long)lane * 64);
#pragma unroll
        for (int k = 0; k < 16; ++k) {
            const float4 wv = wr[k];
#pragma unroll
            for (int rr = 0; rr < 4; ++rr) {
                const float4 xv = ((const float4*)s_d2[R + rr])[k];
                a[rr] += wv.x * xv.x + wv.y * xv.y + wv.z * xv.z + wv.w * xv.w;
            }
        }
#pragma unroll
        for (int rr = 0; rr < 4; ++rr) out[(base + R + rr) * NOUT + lane] = a[rr];
    }
}

// ---------------------------------------------------------------------------
extern "C" void kernel_launch(void* const* d_in, const int* in_sizes, int n_in,
                              void* d_out, int out_size, void* d_ws, size_t ws_size,
                              hipStream_t stream) {
    const float* x = (const float*)d_in[0];
    const float* W_in = (const float*)d_in[1];
    const float* b_in = (const float*)d_in[2];
    const float* g_in = (const float*)d_in[3];
    const float* be_in = (const float*)d_in[4];
    const float* Wih0 = (const float*)d_in[5];
    const float* Whh0 = (const float*)d_in[6];
    const float* bih0 = (const float*)d_in[7];
    const float* bhh0 = (const float*)d_in[8];
    const float* Wih1 = (const float*)d_in[9];
    const float* Whh1 = (const float*)d_in[10];
    const float* bih1 = (const float*)d_in[11];
    const float* bhh1 = (const float*)d_in[12];
    const float* g_ln = (const float*)d_in[13];
    const float* be_ln = (const float*)d_in[14];
    const float* W_d1 = (const float*)d_in[15];
    const float* b_d1 = (const float*)d_in[16];
    const float* W_d2 = (const float*)d_in[17];
    const float* b_d2 = (const float*)d_in[18];
    const float* W_d3 = (const float*)d_in[19];
    const float* b_d3 = (const float*)d_in[20];
    float* out = (float*)d_out;

    // workspace: aux | Uhat | wb(3x512x128 bf16) | stats | hs0 | hlast
    char* w = (char*)d_ws;
    float* aux = (float*)w;               w += 512;
    u16* Uhat = (u16*)w;                  w += 512 * 32 * sizeof(u16);
    u16* wb = (u16*)w;                    w += 3 * 512 * 128 * sizeof(u16);
    float2* stats = (float2*)w;           w += (size_t)B * T * sizeof(float2);
    u16* hs0 = (u16*)w;                   w += (size_t)B * T * H * sizeof(u16);
    u16* hlast = (u16*)w;
    u16* Whh0b = wb;
    u16* Wih1b = wb + 65536;
    u16* Whh1b = wb + 131072;

    prep_aux<<<1, 512, 0, stream>>>(W_in, b_in, g_in, be_in, Wih0, aux, Uhat);
    cvt3<<<192, 256, 0, stream>>>(Whh0, Wih1, Whh1, wb);
    prep_stats<<<(B * T) / 256, 256, 0, stream>>>(x, aux, stats);
    lstm_rec_l1<<<B / 32, 512, 0, stream>>>(x, stats, Uhat, Whh0b, bih0, bhh0, hs0);
    lstm_rec_l2<<<B / 32, 512, 0, stream>>>(Wih1b, Whh1b, bih1, bhh1, hs0, hlast);
    dense_head<<<B / 16, 256, 0, stream>>>(hlast, g_ln, be_ln, W_d1, b_d1, W_d2, b_d2,
                                           W_d3, b_d3, out);
}